// Round 1
// baseline (463.461 us; speedup 1.0000x reference)
//
#include <hip/hip_runtime.h>
#include <hip/hip_bf16.h>
#include <stdint.h>

// LinearAttention on MI355X (gfx950)
// x:[4,4096,1024]f32  w_qkv:[3072,1024]f32  w_proj:[1024,1024]f32  b_proj:[1024]f32
// out:[4,4096,1024]f32

typedef unsigned short u16;
typedef __attribute__((ext_vector_type(4))) float f32x4;
typedef __attribute__((ext_vector_type(8))) __bf16 bf16x8;
typedef __attribute__((ext_vector_type(4))) unsigned short us4;
typedef __attribute__((ext_vector_type(8))) unsigned short us8;

typedef __attribute__((address_space(3))) unsigned as3u;
typedef const __attribute__((address_space(1))) unsigned as1u;

__device__ __forceinline__ float bf2f(u16 u) {
  union { unsigned i; float f; } x; x.i = ((unsigned)u) << 16; return x.f;
}
__device__ __forceinline__ u16 f2bf(float f) {
  union { float f; unsigned i; } x; x.f = f;
  return (u16)((x.i + 0x7FFFu + ((x.i >> 16) & 1u)) >> 16);
}
__device__ __forceinline__ void gload16(const u16* g, u16* l) {
  __builtin_amdgcn_global_load_lds((as1u*)g, (as3u*)l, 16, 0, 0);
}
__device__ __forceinline__ bf16x8 ld8(const u16* p) { return *(const bf16x8*)p; }

// ---------------- fp32 -> bf16 convert (vector x4) ----------------
__global__ __launch_bounds__(256) void cvt_kernel(const float* __restrict__ src,
                                                  u16* __restrict__ dst, int n4) {
  int i = blockIdx.x * 256 + threadIdx.x;
  if (i < n4) {
    f32x4 v = ((const f32x4*)src)[i];
    us4 o;
    o[0] = f2bf(v[0]); o[1] = f2bf(v[1]); o[2] = f2bf(v[2]); o[3] = f2bf(v[3]);
    ((us4*)dst)[i] = o;
  }
}

// ---------------- 128x128-tile bf16 MFMA GEMM  (m97 structure) ----------------
// C[m,c] = sum_k A[m,k]*B[c,k]   (both row-major, K contiguous)
// EPI==0: qkv epilogue -> elu+1 on q,k; scatter to q/k/v [B,H,N,D] bf16
// EPI==1: proj epilogue -> + bias, fp32 out [M,1024]
template <int EPI>
__global__ __launch_bounds__(256) void gemm128(
    const u16* __restrict__ A, const u16* __restrict__ B, int Ncols, int K,
    u16* __restrict__ oQ, u16* __restrict__ oK, u16* __restrict__ oV,
    const float* __restrict__ bias, float* __restrict__ oF) {
  __shared__ u16 As[128 * 64];
  __shared__ u16 Bs[128 * 64];
  const int nTn = Ncols >> 7;
  const int tm = blockIdx.x / nTn, tn = blockIdx.x % nTn;
  const int m0 = tm << 7, n0 = tn << 7;
  const int t = threadIdx.x;
  const int w = t >> 6, lane = t & 63;
  const int wr = w >> 1, wc = w & 1;
  const int l15 = lane & 15, l4 = lane >> 4;

  f32x4 acc[4][4] = {};
  const int kT = K >> 6;
  for (int kt = 0; kt < kT; ++kt) {
    __syncthreads();  // all waves done reading LDS from previous iter
    // stage A,B tiles: 128 rows x 64 cols bf16 each; 1024 16B-chunks per tile
    #pragma unroll
    for (int i = 0; i < 4; ++i) {
      int c = i * 256 + t;          // chunk id 0..1023
      int row = c >> 3, q8 = c & 7; // 8 chunks per row
      gload16(A + (size_t)(m0 + row) * K + kt * 64 + q8 * 8,
              &As[(i * 256 + w * 64) * 8]);  // wave-uniform LDS base
      gload16(B + (size_t)(n0 + row) * K + kt * 64 + q8 * 8,
              &Bs[(i * 256 + w * 64) * 8]);
    }
    __syncthreads();  // compiler drains vmcnt before barrier
    #pragma unroll
    for (int kk = 0; kk < 2; ++kk) {
      bf16x8 a[4], b[4];
      #pragma unroll
      for (int i = 0; i < 4; ++i)
        a[i] = ld8(&As[(wr * 64 + i * 16 + l15) * 64 + kk * 32 + l4 * 8]);
      #pragma unroll
      for (int j = 0; j < 4; ++j)
        b[j] = ld8(&Bs[(wc * 64 + j * 16 + l15) * 64 + kk * 32 + l4 * 8]);
      #pragma unroll
      for (int i = 0; i < 4; ++i)
        #pragma unroll
        for (int j = 0; j < 4; ++j)
          acc[i][j] = __builtin_amdgcn_mfma_f32_16x16x32_bf16(a[i], b[j], acc[i][j], 0, 0, 0);
    }
  }

  // epilogue: D frag mapping col=lane&15, row=(lane>>4)*4+reg  [HW-verified]
  #pragma unroll
  for (int i = 0; i < 4; ++i) {
    const int mbase = m0 + wr * 64 + i * 16 + l4 * 4;
    #pragma unroll
    for (int j = 0; j < 4; ++j) {
      const int col = n0 + wc * 64 + j * 16 + l15;
      #pragma unroll
      for (int r = 0; r < 4; ++r) {
        float val = acc[i][j][r];
        const int m = mbase + r;
        if constexpr (EPI == 0) {
          const int part = col >> 10, cc = col & 1023;
          const int h = cc >> 6, d = cc & 63;
          if (part < 2) val = val > 0.f ? val + 1.f : __expf(val);  // elu(x)+1
          const int b = m >> 12, n = m & 4095;
          size_t off = (((size_t)(b * 16 + h)) * 4096 + n) * 64 + d;
          u16* dst = (part == 0) ? oQ : (part == 1 ? oK : oV);
          dst[off] = f2bf(val);
        } else {
          oF[(size_t)m * 1024 + col] = val + bias[col];
        }
      }
    }
  }
}

// ---------------- kv = k^T v  and  ksum = sum_n k  (per b,h) ----------------
// grid: 64 (b,h) x 4 n-chunks = 256 blocks, 256 threads (16 d-groups x 16 e-groups)
__global__ __launch_bounds__(256) void kv_ksum(const u16* __restrict__ kin,
                                               const u16* __restrict__ vin,
                                               float* __restrict__ kv,
                                               float* __restrict__ ksum) {
  __shared__ u16 kt[64 * 64];
  __shared__ u16 vt[64 * 64];
  const int blk = blockIdx.x;
  const int bh = blk >> 2, chunk = blk & 3;
  const u16* kp = kin + ((size_t)bh * 4096 + chunk * 1024) * 64;
  const u16* vp = vin + ((size_t)bh * 4096 + chunk * 1024) * 64;
  const int t = threadIdx.x;
  const int td = t & 15, te = t >> 4;
  float acc[4][4] = {};
  float ks[4] = {0.f, 0.f, 0.f, 0.f};
  for (int tile = 0; tile < 16; ++tile) {
    __syncthreads();
    {  // stage 64x64 bf16 tiles of k and v (coalesced 16B)
      const us8* sk = (const us8*)(kp + tile * 4096);
      const us8* sv = (const us8*)(vp + tile * 4096);
      ((us8*)kt)[t] = sk[t];
      ((us8*)kt)[t + 256] = sk[t + 256];
      ((us8*)vt)[t] = sv[t];
      ((us8*)vt)[t + 256] = sv[t + 256];
    }
    __syncthreads();
    #pragma unroll 4
    for (int n = 0; n < 64; ++n) {
      us4 k4 = *(const us4*)&kt[n * 64 + td * 4];
      us4 v4 = *(const us4*)&vt[n * 64 + te * 4];
      float kf[4], vf[4];
      #pragma unroll
      for (int j = 0; j < 4; ++j) { kf[j] = bf2f(k4[j]); vf[j] = bf2f(v4[j]); }
      #pragma unroll
      for (int j = 0; j < 4; ++j) ks[j] += kf[j];
      #pragma unroll
      for (int i = 0; i < 4; ++i)
        #pragma unroll
        for (int j = 0; j < 4; ++j) acc[i][j] += kf[i] * vf[j];
    }
  }
  float* kvp = kv + (size_t)bh * 4096;
  #pragma unroll
  for (int i = 0; i < 4; ++i)
    #pragma unroll
    for (int j = 0; j < 4; ++j)
      atomicAdd(&kvp[(td * 4 + i) * 64 + (te * 4 + j)], acc[i][j]);
  if (te == 0) {
    #pragma unroll
    for (int j = 0; j < 4; ++j) atomicAdd(&ksum[bh * 64 + td * 4 + j], ks[j]);
  }
}

// ---------------- num = q@kv, z = 1/(q.ksum+eps), attn = num*z ----------------
// grid: 64 (b,h) x 16 chunks = 1024 blocks; 256 threads, one n-row per thread
__global__ __launch_bounds__(256) void num_z(const u16* __restrict__ qin,
                                             const float* __restrict__ kv,
                                             const float* __restrict__ ksum,
                                             u16* __restrict__ attn) {
  __shared__ float kvs[4096];
  __shared__ float kss[64];
  const int blk = blockIdx.x;
  const int bh = blk >> 4, chunk = blk & 15;
  const int t = threadIdx.x;
  {  // stage kv (16KB) and ksum
    const f32x4* src = (const f32x4*)(kv + (size_t)bh * 4096);
    #pragma unroll
    for (int i = 0; i < 4; ++i) ((f32x4*)kvs)[i * 256 + t] = src[i * 256 + t];
    if (t < 16) ((f32x4*)kss)[t] = ((const f32x4*)(ksum + bh * 64))[t];
  }
  __syncthreads();
  const int n = chunk * 256 + t;
  const u16* qp = qin + ((size_t)bh * 4096 + n) * 64;
  float z = 0.f;
  float num[64] = {};
  for (int db = 0; db < 8; ++db) {  // 8 d-values per block of the d-loop
    us8 u = ((const us8*)qp)[db];
    float q8[8];
    #pragma unroll
    for (int j = 0; j < 8; ++j) q8[j] = bf2f(u[j]);
    #pragma unroll
    for (int dj = 0; dj < 8; ++dj) {
      const float qd = q8[dj];
      z += qd * kss[db * 8 + dj];
      const f32x4* row = (const f32x4*)&kvs[(db * 8 + dj) * 64];
      #pragma unroll
      for (int e4 = 0; e4 < 16; ++e4) {
        f32x4 kv4 = row[e4];  // wave-uniform address -> LDS broadcast
        num[e4 * 4 + 0] += qd * kv4[0];
        num[e4 * 4 + 1] += qd * kv4[1];
        num[e4 * 4 + 2] += qd * kv4[2];
        num[e4 * 4 + 3] += qd * kv4[3];
      }
    }
  }
  const float zz = 1.f / (z + 1e-6f);
  const int b = bh >> 4, h = bh & 15;
  u16* op = attn + (((size_t)b * 4096 + n) * 1024 + h * 64);
  #pragma unroll
  for (int i = 0; i < 8; ++i) {
    us8 o;
    #pragma unroll
    for (int j = 0; j < 8; ++j) o[j] = f2bf(num[i * 8 + j] * zz);
    ((us8*)op)[i] = o;
  }
}

extern "C" void kernel_launch(void* const* d_in, const int* in_sizes, int n_in,
                              void* d_out, int out_size, void* d_ws, size_t ws_size,
                              hipStream_t stream) {
  const float* x = (const float*)d_in[0];
  const float* w_qkv = (const float*)d_in[1];
  const float* w_proj = (const float*)d_in[2];
  const float* b_proj = (const float*)d_in[3];
  float* out = (float*)d_out;
  char* ws = (char*)d_ws;

  // workspace layout (bytes)
  u16* xb     = (u16*)(ws);                    // 32 MB  (x bf16; reused as attn)
  u16* wqkvb  = (u16*)(ws + 33554432);         // 6 MB
  u16* wprojb = (u16*)(ws + 39845888);         // 2 MB
  u16* q      = (u16*)(ws + 41943040);         // 32 MB
  u16* k      = (u16*)(ws + 75497472);         // 32 MB
  u16* v      = (u16*)(ws + 109051904);        // 32 MB
  float* kvb  = (float*)(ws + 142606336);      // 1 MB  [B,H,64,64] fp32
  float* ksum = (float*)(ws + 143654912);      // 16 KB [B,H,64]
  u16* attn   = xb;                            // alias: xb dead after gemm1

  // 1) convert inputs to bf16
  cvt_kernel<<<16384, 256, 0, stream>>>(x, xb, 4194304);
  cvt_kernel<<<3072, 256, 0, stream>>>(w_qkv, wqkvb, 786432);
  cvt_kernel<<<1024, 256, 0, stream>>>(w_proj, wprojb, 262144);
  // 2) qkv GEMM + elu+1 epilogue -> q,k,v [B,H,N,D] bf16
  gemm128<0><<<128 * 24, 256, 0, stream>>>(xb, wqkvb, 3072, 1024, q, k, v, nullptr, nullptr);
  // 3) kv outer-product aggregation + ksum (fp32 atomics; ws poisoned -> zero first)
  hipMemsetAsync(kvb, 0, (64 * 64 * 64 + 64 * 64) * sizeof(float), stream);
  kv_ksum<<<256, 256, 0, stream>>>(k, v, kvb, ksum);
  // 4) numerator + normalizer -> attn [B,N,C] bf16
  num_z<<<1024, 256, 0, stream>>>(q, kvb, ksum, attn);
  // 5) output projection + bias -> fp32 out
  gemm128<1><<<128 * 8, 256, 0, stream>>>(attn, wprojb, 1024, 1024, nullptr, nullptr, nullptr,
                                          b_proj, out);
}

// Round 2
// 413.008 us; speedup vs baseline: 1.1222x; 1.1222x over previous
//
#include <hip/hip_runtime.h>
#include <hip/hip_bf16.h>
#include <stdint.h>

// LinearAttention on MI355X (gfx950)
// x:[4,4096,1024]f32  w_qkv:[3072,1024]f32  w_proj:[1024,1024]f32  b_proj:[1024]f32
// out:[4,4096,1024]f32

typedef unsigned short u16;
typedef __attribute__((ext_vector_type(4))) float f32x4;
typedef __attribute__((ext_vector_type(8))) __bf16 bf16x8;
typedef __attribute__((ext_vector_type(4))) unsigned short us4;
typedef __attribute__((ext_vector_type(8))) unsigned short us8;

typedef __attribute__((address_space(3))) unsigned as3u;
typedef const __attribute__((address_space(1))) unsigned as1u;

__device__ __forceinline__ float bf2f(u16 u) {
  union { unsigned i; float f; } x; x.i = ((unsigned)u) << 16; return x.f;
}
__device__ __forceinline__ u16 f2bf(float f) {
  union { float f; unsigned i; } x; x.f = f;
  return (u16)((x.i + 0x7FFFu + ((x.i >> 16) & 1u)) >> 16);
}
__device__ __forceinline__ void gload16(const u16* g, u16* l) {
  __builtin_amdgcn_global_load_lds((as1u*)g, (as3u*)l, 16, 0, 0);
}
__device__ __forceinline__ bf16x8 ld8(const u16* p) { return *(const bf16x8*)p; }

// ---------------- fp32 -> bf16 convert (vector x4) ----------------
__global__ __launch_bounds__(256) void cvt_kernel(const float* __restrict__ src,
                                                  u16* __restrict__ dst, int n4) {
  int i = blockIdx.x * 256 + threadIdx.x;
  if (i < n4) {
    f32x4 v = ((const f32x4*)src)[i];
    us4 o;
    o[0] = f2bf(v[0]); o[1] = f2bf(v[1]); o[2] = f2bf(v[2]); o[3] = f2bf(v[3]);
    ((us4*)dst)[i] = o;
  }
}

// ---------------- 128x128-tile bf16 MFMA GEMM  (m97 structure) ----------------
// C[m,c] = sum_k A[m,k]*B[c,k]   (both row-major, K contiguous)
// EPI==0: qkv epilogue -> elu+1 on q,k; q n-major [B,H,N,D]; k,v d-major [B,H,D,N]
// EPI==1: proj epilogue -> + bias, fp32 out [M,1024]
template <int EPI>
__global__ __launch_bounds__(256) void gemm128(
    const u16* __restrict__ A, const u16* __restrict__ B, int Ncols, int K,
    u16* __restrict__ oQ, u16* __restrict__ oKT, u16* __restrict__ oVT,
    const float* __restrict__ bias, float* __restrict__ oF) {
  __shared__ u16 As[128 * 64];
  __shared__ u16 Bs[128 * 64];
  const int nTn = Ncols >> 7;
  const int tm = blockIdx.x / nTn, tn = blockIdx.x % nTn;
  const int m0 = tm << 7, n0 = tn << 7;
  const int t = threadIdx.x;
  const int w = t >> 6, lane = t & 63;
  const int wr = w >> 1, wc = w & 1;
  const int l15 = lane & 15, l4 = lane >> 4;

  f32x4 acc[4][4] = {};
  const int kT = K >> 6;
  for (int kt = 0; kt < kT; ++kt) {
    __syncthreads();  // all waves done reading LDS from previous iter
    #pragma unroll
    for (int i = 0; i < 4; ++i) {
      int c = i * 256 + t;          // chunk id 0..1023
      int row = c >> 3, q8 = c & 7; // 8 chunks per row
      gload16(A + (size_t)(m0 + row) * K + kt * 64 + q8 * 8,
              &As[(i * 256 + w * 64) * 8]);  // wave-uniform LDS base
      gload16(B + (size_t)(n0 + row) * K + kt * 64 + q8 * 8,
              &Bs[(i * 256 + w * 64) * 8]);
    }
    __syncthreads();  // compiler drains vmcnt before barrier
    #pragma unroll
    for (int kk = 0; kk < 2; ++kk) {
      bf16x8 a[4], b[4];
      #pragma unroll
      for (int i = 0; i < 4; ++i)
        a[i] = ld8(&As[(wr * 64 + i * 16 + l15) * 64 + kk * 32 + l4 * 8]);
      #pragma unroll
      for (int j = 0; j < 4; ++j)
        b[j] = ld8(&Bs[(wc * 64 + j * 16 + l15) * 64 + kk * 32 + l4 * 8]);
      #pragma unroll
      for (int i = 0; i < 4; ++i)
        #pragma unroll
        for (int j = 0; j < 4; ++j)
          acc[i][j] = __builtin_amdgcn_mfma_f32_16x16x32_bf16(a[i], b[j], acc[i][j], 0, 0, 0);
    }
  }

  // epilogue: D frag mapping col=lane&15, row=(lane>>4)*4+reg  [HW-verified]
  if constexpr (EPI == 0) {
    #pragma unroll
    for (int j = 0; j < 4; ++j) {
      const int col = n0 + wc * 64 + j * 16 + l15;
      const int part = col >> 10, cc = col & 1023;
      const int h = cc >> 6, d = cc & 63;
      #pragma unroll
      for (int i = 0; i < 4; ++i) {
        const int mbase = m0 + wr * 64 + i * 16 + l4 * 4;
        const int b = mbase >> 12, n = mbase & 4095;
        const int bh = b * 16 + h;
        if (part == 0) {
          #pragma unroll
          for (int r = 0; r < 4; ++r) {
            float val = acc[i][j][r];
            val = val > 0.f ? val + 1.f : __expf(val);  // elu(x)+1
            oQ[(((size_t)bh) * 4096 + n + r) * 64 + d] = f2bf(val);
          }
        } else {
          us4 o;
          #pragma unroll
          for (int r = 0; r < 4; ++r) {
            float val = acc[i][j][r];
            if (part == 1) val = val > 0.f ? val + 1.f : __expf(val);
            o[r] = f2bf(val);
          }
          u16* dst = (part == 1) ? oKT : oVT;
          *(us4*)&dst[(((size_t)bh) * 64 + d) * 4096 + n] = o;
        }
      }
    }
  } else {
    #pragma unroll
    for (int i = 0; i < 4; ++i) {
      const int mbase = m0 + wr * 64 + i * 16 + l4 * 4;
      #pragma unroll
      for (int j = 0; j < 4; ++j) {
        const int col = n0 + wc * 64 + j * 16 + l15;
        #pragma unroll
        for (int r = 0; r < 4; ++r)
          oF[(size_t)(mbase + r) * 1024 + col] = acc[i][j][r] + bias[col];
      }
    }
  }
}

// ---------------- kv = kT @ vT^T per (b,h), split-K MFMA + ksum ----------------
// grid: 64 bh x 16 splits; 256 thr (4 waves, 2x2 of 32x32)
// kT,vT: [B,H,64,4096] bf16.  out: kv_part[s][bh][e][d] fp32, ksum_part[s][bh][d] fp32
__global__ __launch_bounds__(256) void kv_mfma(const u16* __restrict__ kTg,
                                               const u16* __restrict__ vTg,
                                               float* __restrict__ kv_part,
                                               float* __restrict__ ksum_part) {
  __shared__ u16 kTl[64 * 256];
  __shared__ u16 vTl[64 * 256];
  const int blk = blockIdx.x;
  const int bh = blk >> 4, s = blk & 15;
  const int n0 = s * 256;
  const int t = threadIdx.x;
  const int w = t >> 6, lane = t & 63;
  const int wr = w >> 1, wc = w & 1;
  const int l15 = lane & 15, l4 = lane >> 4;

  const u16* kg = kTg + ((size_t)bh * 64) * 4096 + n0;
  const u16* vg = vTg + ((size_t)bh * 64) * 4096 + n0;
  // stage [64 rows][256 cols] bf16 = 2048 16B-chunks each; XOR-swizzled source
  #pragma unroll
  for (int i = 0; i < 8; ++i) {
    int c = i * 256 + t;
    int row = c >> 5, ch = c & 31;                 // 32 chunks/row
    int sch = (ch & ~7) | ((ch ^ row) & 7);        // inverse swizzle on source
    gload16(kg + (size_t)row * 4096 + sch * 8, &kTl[(i * 256 + w * 64) * 8]);
    gload16(vg + (size_t)row * 4096 + sch * 8, &vTl[(i * 256 + w * 64) * 8]);
  }
  __syncthreads();

  // ksum partial: row = t>>2, quarter = t&3; rotation avoids same-column banks;
  // physical row is a permutation of logical row -> sum invariant
  {
    const int row = t >> 2, q4 = t & 3;
    float sum = 0.f;
    #pragma unroll
    for (int j = 0; j < 8; ++j) {
      int p = q4 * 8 + ((j + row) & 7);
      us8 u = *(const us8*)&kTl[row * 256 + p * 8];
      #pragma unroll
      for (int x = 0; x < 8; ++x) sum += bf2f(u[x]);
    }
    sum += __shfl_xor(sum, 1);
    sum += __shfl_xor(sum, 2);
    if ((t & 3) == 0) ksum_part[((size_t)s * 64 + bh) * 64 + row] = sum;
  }

  f32x4 acc[2][2] = {};
  #pragma unroll
  for (int kk = 0; kk < 8; ++kk) {
    bf16x8 a[2], b[2];
    #pragma unroll
    for (int i = 0; i < 2; ++i) {
      int row = wr * 32 + i * 16 + l15;
      int p = (kk * 4 + l4) ^ (row & 7);
      a[i] = ld8(&kTl[row * 256 + p * 8]);
    }
    #pragma unroll
    for (int j = 0; j < 2; ++j) {
      int row = wc * 32 + j * 16 + l15;
      int p = (kk * 4 + l4) ^ (row & 7);
      b[j] = ld8(&vTl[row * 256 + p * 8]);
    }
    #pragma unroll
    for (int i = 0; i < 2; ++i)
      #pragma unroll
      for (int j = 0; j < 2; ++j)
        acc[i][j] = __builtin_amdgcn_mfma_f32_16x16x32_bf16(a[i], b[j], acc[i][j], 0, 0, 0);
  }
  // kv[d][e] written TRANSPOSED as kv_part[s][bh][e][d] (num wants B[e,d]=kv[d,e])
  float* dst = kv_part + ((size_t)s * 64 + bh) * 4096;
  #pragma unroll
  for (int i = 0; i < 2; ++i)
    #pragma unroll
    for (int j = 0; j < 2; ++j)
      #pragma unroll
      for (int r = 0; r < 4; ++r) {
        int d = wr * 32 + i * 16 + l4 * 4 + r;
        int e = wc * 32 + j * 16 + l15;
        dst[e * 64 + d] = acc[i][j][r];
      }
}

// ---------------- reduce split-K partials -> kvT bf16 [bh][80][64] ----------------
// rows 0..63 = kv^T (e-major), row 64 = ksum, rows 65..79 = 0
__global__ __launch_bounds__(256) void cvt_kv(const float* __restrict__ kv_part,
                                              const float* __restrict__ ksum_part,
                                              u16* __restrict__ kvTb) {
  const int bh = blockIdx.x;
  const int t = threadIdx.x;
  #pragma unroll
  for (int i = 0; i < 20; ++i) {
    int idx = i * 256 + t;
    int row = idx >> 6, d = idx & 63;
    float s = 0.f;
    if (row < 64) {
      #pragma unroll
      for (int p = 0; p < 16; ++p)
        s += kv_part[((size_t)p * 64 + bh) * 4096 + idx];
    } else if (row == 64) {
      #pragma unroll
      for (int p = 0; p < 16; ++p)
        s += ksum_part[((size_t)p * 64 + bh) * 64 + d];
    }
    kvTb[(size_t)bh * 5120 + idx] = f2bf(s);
  }
}

// ---------------- num = q @ kvT, z via ksum-column, attn = num*z ----------------
// grid: 64 bh x 32 n-chunks; 256 thr (4 waves, wave w owns rows [w*32,w*32+32))
__global__ __launch_bounds__(256) void numz_mfma(const u16* __restrict__ qg,
                                                 const u16* __restrict__ kvTb,
                                                 u16* __restrict__ attn) {
  __shared__ u16 ql[128 * 64];
  __shared__ u16 bl[80 * 64];
  const int blk = blockIdx.x;
  const int bh = blk >> 5, c5 = blk & 31;
  const int t = threadIdx.x;
  const int w = t >> 6, lane = t & 63;
  const int l15 = lane & 15, l4 = lane >> 4;
  const int bb = bh >> 4, h = bh & 15;

  const u16* qp = qg + ((size_t)bh * 4096 + c5 * 128) * 64;
  #pragma unroll
  for (int i = 0; i < 4; ++i) {
    int c = i * 256 + t;
    int row = c >> 3, ch = c & 7;  // 8 chunks/row
    gload16(qp + (size_t)row * 64 + ((ch ^ row) & 7) * 8, &ql[(i * 256 + w * 64) * 8]);
  }
  {  // stage B [80][64] via swizzled ds_write (us4 granularity)
    const us4* bsrc = (const us4*)(kvTb + (size_t)bh * 5120);
    #pragma unroll
    for (int i = 0; i < 5; ++i) {
      int idx = i * 256 + t;
      int row = idx >> 4;  // 16 us4 per row
      ((us4*)bl)[idx ^ ((row & 7) << 1)] = bsrc[idx];
    }
  }
  __syncthreads();

  f32x4 acc[2][5] = {};
  #pragma unroll
  for (int kk = 0; kk < 2; ++kk) {
    bf16x8 a[2], b[5];
    #pragma unroll
    for (int i = 0; i < 2; ++i) {
      int row = w * 32 + i * 16 + l15;
      int p = (kk * 4 + l4) ^ (row & 7);
      a[i] = ld8(&ql[row * 64 + p * 8]);
    }
    #pragma unroll
    for (int j = 0; j < 5; ++j) {
      int row = j * 16 + l15;
      int p = (kk * 4 + l4) ^ (row & 7);
      b[j] = ld8(&bl[row * 64 + p * 8]);
    }
    #pragma unroll
    for (int i = 0; i < 2; ++i)
      #pragma unroll
      for (int j = 0; j < 5; ++j)
        acc[i][j] = __builtin_amdgcn_mfma_f32_16x16x32_bf16(a[i], b[j], acc[i][j], 0, 0, 0);
  }

  // col 64 (j=4, l15==0) holds z-denominator; broadcast within 16-lane group
  #pragma unroll
  for (int i = 0; i < 2; ++i)
    #pragma unroll
    for (int r = 0; r < 4; ++r) {
      int m = w * 32 + i * 16 + l4 * 4 + r;
      int n = c5 * 128 + m;
      float zv = __shfl(acc[i][4][r], lane & 48);
      float zz = 1.f / (zv + 1e-6f);
      u16* op = attn + ((size_t)bb * 4096 + n) * 1024 + h * 64;
      #pragma unroll
      for (int j = 0; j < 4; ++j)
        op[j * 16 + l15] = f2bf(acc[i][j][r] * zz);
    }
}

extern "C" void kernel_launch(void* const* d_in, const int* in_sizes, int n_in,
                              void* d_out, int out_size, void* d_ws, size_t ws_size,
                              hipStream_t stream) {
  const float* x = (const float*)d_in[0];
  const float* w_qkv = (const float*)d_in[1];
  const float* w_proj = (const float*)d_in[2];
  const float* b_proj = (const float*)d_in[3];
  float* out = (float*)d_out;
  char* ws = (char*)d_ws;

  // workspace layout (bytes)
  u16* xb        = (u16*)(ws);                 // 32MB  x bf16
  float* kv_part = (float*)(ws);               // alias: 16.8MB, live kv_mfma->cvt_kv
  u16* attn      = (u16*)(ws);                 // alias: 32MB, live numz->proj gemm
  u16* wqkvb     = (u16*)(ws + 33554432);      // 6MB
  u16* wprojb    = (u16*)(ws + 39845888);      // 2MB
  u16* q         = (u16*)(ws + 41943040);      // 32MB [B,H,N,D]
  u16* kT        = (u16*)(ws + 75497472);      // 32MB [B,H,D,N]
  u16* vT        = (u16*)(ws + 109051904);     // 32MB [B,H,D,N]
  float* ksum_p  = (float*)(ws + 142606336);   // 256KB [16][64][64]
  u16* kvTb      = (u16*)(ws + 142868480);     // 640KB [64][80][64]

  // 1) convert inputs to bf16
  cvt_kernel<<<16384, 256, 0, stream>>>(x, xb, 4194304);
  cvt_kernel<<<3072, 256, 0, stream>>>(w_qkv, wqkvb, 786432);
  cvt_kernel<<<1024, 256, 0, stream>>>(w_proj, wprojb, 262144);
  // 2) qkv GEMM + elu+1 epilogue -> q [B,H,N,D], kT/vT [B,H,D,N]
  gemm128<0><<<128 * 24, 256, 0, stream>>>(xb, wqkvb, 3072, 1024, q, kT, vT, nullptr, nullptr);
  // 3) kv = k^T v (split-K MFMA) + ksum partials   (xb dead -> kv_part aliases it)
  kv_mfma<<<1024, 256, 0, stream>>>(kT, vT, kv_part, ksum_p);
  // 4) reduce partials -> kvT bf16 [bh][80][64] (row64=ksum, 65..79=0)
  cvt_kv<<<64, 256, 0, stream>>>(kv_part, ksum_p, kvTb);
  // 5) num/z MFMA -> attn bf16 [B,N,C]  (attn aliases xb; kv_part dead)
  numz_mfma<<<2048, 256, 0, stream>>>(q, kvTb, attn);
  // 6) output projection + bias -> fp32 out
  gemm128<1><<<128 * 8, 256, 0, stream>>>(attn, wprojb, 1024, 1024, nullptr, nullptr, nullptr,
                                          b_proj, out);
}

// Round 3
// 317.224 us; speedup vs baseline: 1.4610x; 1.3019x over previous
//
#include <hip/hip_runtime.h>
#include <hip/hip_bf16.h>
#include <stdint.h>

// LinearAttention on MI355X (gfx950)
// x:[4,4096,1024]f32  w_qkv:[3072,1024]f32  w_proj:[1024,1024]f32  b_proj:[1024]f32
// out:[4,4096,1024]f32

typedef unsigned short u16;
typedef __attribute__((ext_vector_type(4))) float f32x4;
typedef __attribute__((ext_vector_type(8))) __bf16 bf16x8;
typedef __attribute__((ext_vector_type(4))) unsigned short us4;
typedef __attribute__((ext_vector_type(8))) unsigned short us8;

typedef __attribute__((address_space(3))) unsigned as3u;
typedef const __attribute__((address_space(1))) unsigned as1u;

__device__ __forceinline__ float bf2f(u16 u) {
  union { unsigned i; float f; } x; x.i = ((unsigned)u) << 16; return x.f;
}
__device__ __forceinline__ u16 f2bf(float f) {
  union { float f; unsigned i; } x; x.f = f;
  return (u16)((x.i + 0x7FFFu + ((x.i >> 16) & 1u)) >> 16);
}
__device__ __forceinline__ void gload16(const u16* g, u16* l) {
  __builtin_amdgcn_global_load_lds((as1u*)g, (as3u*)l, 16, 0, 0);
}
__device__ __forceinline__ bf16x8 ld8(const u16* p) { return *(const bf16x8*)p; }

#define BAR asm volatile("s_barrier" ::: "memory")
#define VMC4 asm volatile("s_waitcnt vmcnt(4)" ::: "memory")
#define VMC0 asm volatile("s_waitcnt vmcnt(0)" ::: "memory")

// ---------------- fp32 -> bf16 convert (vector x4) ----------------
__global__ __launch_bounds__(256) void cvt_kernel(const float* __restrict__ src,
                                                  u16* __restrict__ dst, int n4) {
  int i = blockIdx.x * 256 + threadIdx.x;
  if (i < n4) {
    f32x4 v = ((const f32x4*)src)[i];
    us4 o;
    o[0] = f2bf(v[0]); o[1] = f2bf(v[1]); o[2] = f2bf(v[2]); o[3] = f2bf(v[3]);
    ((us4*)dst)[i] = o;
  }
}

// ======== 256x256-tile bf16 MFMA GEMM, 8-phase schedule (m201 template) ========
// C[m,c] = sum_k A[m,k]*B[c,k], K=1024. 512 thr = 8 waves (2M x 4N).
// LDS: 2 dbuf x (A[256][64] + B[256][64]) = 128 KiB, XOR chunk-swizzle.
// EPI==0: qkv epilogue (elu+1 on q,k; q [B,H,N,D]; kT/vT [B,H,D,N])
// EPI==1: proj epilogue (+bias, fp32 out)
template <int EPI>
__global__ __launch_bounds__(512) void gemm256(
    const u16* __restrict__ A, const u16* __restrict__ B, int Ncols,
    u16* __restrict__ oQ, u16* __restrict__ oKT, u16* __restrict__ oVT,
    const float* __restrict__ bias, float* __restrict__ oF) {
  constexpr int K = 1024;
  constexpr int NITER = 8;  // 16 K-tiles, 2 per iteration
  __shared__ u16 lds[2][2][256 * 64];  // [buf][0=A,1=B]

  const int nTn = Ncols >> 8;
  const int nwg = gridDim.x;                 // multiple of 8
  const int bid = blockIdx.x;
  const int swz = (bid & 7) * (nwg >> 3) + (bid >> 3);  // T1 XCD swizzle
  const int tm = swz / nTn, tn = swz % nTn;
  const int m0 = tm << 8, n0 = tn << 8;
  const int t = threadIdx.x;
  const int w = t >> 6, lane = t & 63;
  const int wm = w >> 2, wn = w & 3;
  const int l15 = lane & 15, l4 = lane >> 4;

  const u16* Ab = A + (size_t)m0 * K;
  const u16* Bb = B + (size_t)n0 * K;

  // staging source offsets: load l covers chunk c = l*512+t; row=c>>3, ch=c&7
  // physical LDS is linear; source chunk pre-swizzled: sch = ch ^ (row&7)
  int srcoff[2][2];
  #pragma unroll
  for (int l = 0; l < 2; ++l) {
    int c = l * 512 + t;
    int row = c >> 3, ch = c & 7;
    #pragma unroll
    for (int h = 0; h < 2; ++h) {
      int r = row + h * 128;
      srcoff[l][h] = r * K + (ch ^ (r & 7)) * 8;
    }
  }

#define STAGE(mat, buf, h, kt)                                                \
  {                                                                           \
    const u16* gsrc = ((mat) ? Bb : Ab) + (kt) * 64;                          \
    _Pragma("unroll") for (int l = 0; l < 2; ++l)                             \
        gload16(gsrc + srcoff[l][h],                                          \
                &lds[buf][mat][(l * 512 + w * 64) * 8 + (h) * 128 * 64]);     \
  }

#define LDA(buf, q)                                                           \
  _Pragma("unroll") for (int i = 0; i < 2; ++i)                               \
  _Pragma("unroll") for (int kk = 0; kk < 2; ++kk) {                          \
    int row = wm * 128 + (q) * 32 + i * 16 + l15;                             \
    int ch = (kk * 4 + l4) ^ (row & 7);                                       \
    a[i][kk] = ld8(&lds[buf][0][row * 64 + ch * 8]);                          \
  }

#define LDB(buf)                                                              \
  _Pragma("unroll") for (int j = 0; j < 4; ++j)                               \
  _Pragma("unroll") for (int kk = 0; kk < 2; ++kk) {                          \
    int row = wn * 64 + j * 16 + l15;                                         \
    int ch = (kk * 4 + l4) ^ (row & 7);                                       \
    b[j][kk] = ld8(&lds[buf][1][row * 64 + ch * 8]);                          \
  }

#define MFMA16(q)                                                             \
  __builtin_amdgcn_s_setprio(1);                                              \
  _Pragma("unroll") for (int i = 0; i < 2; ++i)                               \
  _Pragma("unroll") for (int kk = 0; kk < 2; ++kk)                            \
  _Pragma("unroll") for (int j = 0; j < 4; ++j)                               \
    acc[(q) * 2 + i][j] = __builtin_amdgcn_mfma_f32_16x16x32_bf16(            \
        a[i][kk], b[j][kk], acc[(q) * 2 + i][j], 0, 0, 0);                    \
  __builtin_amdgcn_s_setprio(0);

  f32x4 acc[8][4] = {};
  bf16x8 a[2][2], b[4][2];

  // prologue: tile0 (B then A) -> buf0, tile1 B -> buf1.  12 loads out.
  STAGE(1, 0, 0, 0); STAGE(1, 0, 1, 0);
  STAGE(0, 0, 0, 0); STAGE(0, 0, 1, 0);
  STAGE(1, 1, 0, 1); STAGE(1, 1, 1, 1);
  VMC4;  // drain B(0),A(0); leave B(1) in flight
  BAR;

  for (int J = 0; J < NITER; ++J) {
    const int t2 = 2 * J + 2, t3 = 2 * J + 3;
    const bool more = (J < NITER - 1);
    // ---- tile 2J from buf0 ----
    // phase 1: all-B + A.q0 reads; stage A(2J+1).H0 -> buf1.A (dead since prev p8)
    LDB(0); LDA(0, 0);
    STAGE(0, 1, 0, 2 * J + 1);
    BAR; MFMA16(0); BAR;
    // phase 2
    LDA(0, 1);
    STAGE(0, 1, 1, 2 * J + 1);
    BAR; MFMA16(1); BAR;
    // phase 3: buf0.B dead since p1 -> stage B(2J+2)
    LDA(0, 2);
    if (more) STAGE(1, 0, 0, t2);
    BAR; MFMA16(2); BAR;
    // phase 4
    LDA(0, 3);
    if (more) STAGE(1, 0, 1, t2);
    BAR; MFMA16(3);
    if (more) { VMC4; } else { VMC0; }  // drain B(2J+1)+A(2J+1); leave B(2J+2)
    BAR;
    // ---- tile 2J+1 from buf1 ----
    // phase 5: buf0.A dead since p4 -> stage A(2J+2)
    LDB(1); LDA(1, 0);
    if (more) STAGE(0, 0, 0, t2);
    BAR; MFMA16(0); BAR;
    // phase 6
    LDA(1, 1);
    if (more) STAGE(0, 0, 1, t2);
    BAR; MFMA16(1); BAR;
    // phase 7: buf1.B dead since p5 -> stage B(2J+3)
    LDA(1, 2);
    if (more) STAGE(1, 1, 0, t3);
    BAR; MFMA16(2); BAR;
    // phase 8
    LDA(1, 3);
    if (more) STAGE(1, 1, 1, t3);
    BAR; MFMA16(3);
    if (more) { VMC4; } else { VMC0; }  // drain B(2J+2)+A(2J+2); leave B(2J+3)
    BAR;
  }

  // epilogue: D frag mapping col=lane&15, row=(lane>>4)*4+reg  [HW-verified]
  if constexpr (EPI == 0) {
    #pragma unroll
    for (int j = 0; j < 4; ++j) {
      const int col = n0 + wn * 64 + j * 16 + l15;
      const int part = col >> 10, cc = col & 1023;
      const int h = cc >> 6, d = cc & 63;
      #pragma unroll
      for (int fi = 0; fi < 8; ++fi) {
        const int mbase = m0 + wm * 128 + fi * 16 + l4 * 4;
        const int bb = mbase >> 12, n = mbase & 4095;
        const int bh = bb * 16 + h;
        if (part == 0) {
          #pragma unroll
          for (int r = 0; r < 4; ++r) {
            float val = acc[fi][j][r];
            val = val > 0.f ? val + 1.f : __expf(val);  // elu(x)+1
            oQ[(((size_t)bh) * 4096 + n + r) * 64 + d] = f2bf(val);
          }
        } else {
          us4 o;
          #pragma unroll
          for (int r = 0; r < 4; ++r) {
            float val = acc[fi][j][r];
            if (part == 1) val = val > 0.f ? val + 1.f : __expf(val);
            o[r] = f2bf(val);
          }
          u16* dst = (part == 1) ? oKT : oVT;
          *(us4*)&dst[(((size_t)bh) * 64 + d) * 4096 + n] = o;
        }
      }
    }
  } else {
    #pragma unroll
    for (int fi = 0; fi < 8; ++fi) {
      const int mbase = m0 + wm * 128 + fi * 16 + l4 * 4;
      #pragma unroll
      for (int j = 0; j < 4; ++j) {
        const int col = n0 + wn * 64 + j * 16 + l15;
        #pragma unroll
        for (int r = 0; r < 4; ++r)
          oF[(size_t)(mbase + r) * 1024 + col] = acc[fi][j][r] + bias[col];
      }
    }
  }
#undef STAGE
#undef LDA
#undef LDB
#undef MFMA16
}

// ---------------- kv = kT @ vT^T per (b,h), split-K MFMA + ksum ----------------
__global__ __launch_bounds__(256) void kv_mfma(const u16* __restrict__ kTg,
                                               const u16* __restrict__ vTg,
                                               float* __restrict__ kv_part,
                                               float* __restrict__ ksum_part) {
  __shared__ u16 kTl[64 * 256];
  __shared__ u16 vTl[64 * 256];
  const int blk = blockIdx.x;
  const int bh = blk >> 4, s = blk & 15;
  const int n0 = s * 256;
  const int t = threadIdx.x;
  const int w = t >> 6, lane = t & 63;
  const int wr = w >> 1, wc = w & 1;
  const int l15 = lane & 15, l4 = lane >> 4;

  const u16* kg = kTg + ((size_t)bh * 64) * 4096 + n0;
  const u16* vg = vTg + ((size_t)bh * 64) * 4096 + n0;
  #pragma unroll
  for (int i = 0; i < 8; ++i) {
    int c = i * 256 + t;
    int row = c >> 5, ch = c & 31;
    int sch = (ch & ~7) | ((ch ^ row) & 7);
    gload16(kg + (size_t)row * 4096 + sch * 8, &kTl[(i * 256 + w * 64) * 8]);
    gload16(vg + (size_t)row * 4096 + sch * 8, &vTl[(i * 256 + w * 64) * 8]);
  }
  __syncthreads();

  {
    const int row = t >> 2, q4 = t & 3;
    float sum = 0.f;
    #pragma unroll
    for (int j = 0; j < 8; ++j) {
      int p = q4 * 8 + ((j + row) & 7);
      us8 u = *(const us8*)&kTl[row * 256 + p * 8];
      #pragma unroll
      for (int x = 0; x < 8; ++x) sum += bf2f(u[x]);
    }
    sum += __shfl_xor(sum, 1);
    sum += __shfl_xor(sum, 2);
    if ((t & 3) == 0) ksum_part[((size_t)s * 64 + bh) * 64 + row] = sum;
  }

  f32x4 acc[2][2] = {};
  #pragma unroll
  for (int kk = 0; kk < 8; ++kk) {
    bf16x8 a[2], b[2];
    #pragma unroll
    for (int i = 0; i < 2; ++i) {
      int row = wr * 32 + i * 16 + l15;
      int p = (kk * 4 + l4) ^ (row & 7);
      a[i] = ld8(&kTl[row * 256 + p * 8]);
    }
    #pragma unroll
    for (int j = 0; j < 2; ++j) {
      int row = wc * 32 + j * 16 + l15;
      int p = (kk * 4 + l4) ^ (row & 7);
      b[j] = ld8(&vTl[row * 256 + p * 8]);
    }
    #pragma unroll
    for (int i = 0; i < 2; ++i)
      #pragma unroll
      for (int j = 0; j < 2; ++j)
        acc[i][j] = __builtin_amdgcn_mfma_f32_16x16x32_bf16(a[i], b[j], acc[i][j], 0, 0, 0);
  }
  float* dst = kv_part + ((size_t)s * 64 + bh) * 4096;
  #pragma unroll
  for (int i = 0; i < 2; ++i)
    #pragma unroll
    for (int j = 0; j < 2; ++j)
      #pragma unroll
      for (int r = 0; r < 4; ++r) {
        int d = wr * 32 + i * 16 + l4 * 4 + r;
        int e = wc * 32 + j * 16 + l15;
        dst[e * 64 + d] = acc[i][j][r];
      }
}

// ---------------- reduce split-K partials -> kvT bf16 [bh][80][64] ----------------
__global__ __launch_bounds__(256) void cvt_kv(const float* __restrict__ kv_part,
                                              const float* __restrict__ ksum_part,
                                              u16* __restrict__ kvTb) {
  const int bh = blockIdx.x;
  const int t = threadIdx.x;
  #pragma unroll
  for (int i = 0; i < 20; ++i) {
    int idx = i * 256 + t;
    int row = idx >> 6, d = idx & 63;
    float s = 0.f;
    if (row < 64) {
      #pragma unroll
      for (int p = 0; p < 16; ++p)
        s += kv_part[((size_t)p * 64 + bh) * 4096 + idx];
    } else if (row == 64) {
      #pragma unroll
      for (int p = 0; p < 16; ++p)
        s += ksum_part[((size_t)p * 64 + bh) * 64 + d];
    }
    kvTb[(size_t)bh * 5120 + idx] = f2bf(s);
  }
}

// ---------------- num = q @ kvT, z via ksum-column, attn = num*z ----------------
__global__ __launch_bounds__(256) void numz_mfma(const u16* __restrict__ qg,
                                                 const u16* __restrict__ kvTb,
                                                 u16* __restrict__ attn) {
  __shared__ u16 ql[128 * 64];
  __shared__ u16 bl[80 * 64];
  const int blk = blockIdx.x;
  const int bh = blk >> 5, c5 = blk & 31;
  const int t = threadIdx.x;
  const int w = t >> 6, lane = t & 63;
  const int l15 = lane & 15, l4 = lane >> 4;
  const int bb = bh >> 4, h = bh & 15;

  const u16* qp = qg + ((size_t)bh * 4096 + c5 * 128) * 64;
  #pragma unroll
  for (int i = 0; i < 4; ++i) {
    int c = i * 256 + t;
    int row = c >> 3, ch = c & 7;
    gload16(qp + (size_t)row * 64 + ((ch ^ row) & 7) * 8, &ql[(i * 256 + w * 64) * 8]);
  }
  {
    const us4* bsrc = (const us4*)(kvTb + (size_t)bh * 5120);
    #pragma unroll
    for (int i = 0; i < 5; ++i) {
      int idx = i * 256 + t;
      int row = idx >> 4;
      ((us4*)bl)[idx ^ ((row & 7) << 1)] = bsrc[idx];
    }
  }
  __syncthreads();

  f32x4 acc[2][5] = {};
  #pragma unroll
  for (int kk = 0; kk < 2; ++kk) {
    bf16x8 a[2], b[5];
    #pragma unroll
    for (int i = 0; i < 2; ++i) {
      int row = w * 32 + i * 16 + l15;
      int p = (kk * 4 + l4) ^ (row & 7);
      a[i] = ld8(&ql[row * 64 + p * 8]);
    }
    #pragma unroll
    for (int j = 0; j < 5; ++j) {
      int row = j * 16 + l15;
      int p = (kk * 4 + l4) ^ (row & 7);
      b[j] = ld8(&bl[row * 64 + p * 8]);
    }
    #pragma unroll
    for (int i = 0; i < 2; ++i)
      #pragma unroll
      for (int j = 0; j < 5; ++j)
        acc[i][j] = __builtin_amdgcn_mfma_f32_16x16x32_bf16(a[i], b[j], acc[i][j], 0, 0, 0);
  }

  #pragma unroll
  for (int i = 0; i < 2; ++i)
    #pragma unroll
    for (int r = 0; r < 4; ++r) {
      int m = w * 32 + i * 16 + l4 * 4 + r;
      int n = c5 * 128 + m;
      float zv = __shfl(acc[i][4][r], lane & 48);
      float zz = 1.f / (zv + 1e-6f);
      u16* op = attn + ((size_t)bb * 4096 + n) * 1024 + h * 64;
      #pragma unroll
      for (int j = 0; j < 4; ++j)
        op[j * 16 + l15] = f2bf(acc[i][j][r] * zz);
    }
}

extern "C" void kernel_launch(void* const* d_in, const int* in_sizes, int n_in,
                              void* d_out, int out_size, void* d_ws, size_t ws_size,
                              hipStream_t stream) {
  const float* x = (const float*)d_in[0];
  const float* w_qkv = (const float*)d_in[1];
  const float* w_proj = (const float*)d_in[2];
  const float* b_proj = (const float*)d_in[3];
  float* out = (float*)d_out;
  char* ws = (char*)d_ws;

  // workspace layout (bytes)
  u16* xb        = (u16*)(ws);                 // 32MB  x bf16
  float* kv_part = (float*)(ws);               // alias: 16.8MB, live kv_mfma->cvt_kv
  u16* attn      = (u16*)(ws);                 // alias: 32MB, live numz->proj gemm
  u16* wqkvb     = (u16*)(ws + 33554432);      // 6MB
  u16* wprojb    = (u16*)(ws + 39845888);      // 2MB
  u16* q         = (u16*)(ws + 41943040);      // 32MB [B,H,N,D]
  u16* kT        = (u16*)(ws + 75497472);      // 32MB [B,H,D,N]
  u16* vT        = (u16*)(ws + 109051904);     // 32MB [B,H,D,N]
  float* ksum_p  = (float*)(ws + 142606336);   // 256KB [16][64][64]
  u16* kvTb      = (u16*)(ws + 142868480);     // 640KB [64][80][64]

  // 1) convert inputs to bf16
  cvt_kernel<<<16384, 256, 0, stream>>>(x, xb, 4194304);
  cvt_kernel<<<3072, 256, 0, stream>>>(w_qkv, wqkvb, 786432);
  cvt_kernel<<<1024, 256, 0, stream>>>(w_proj, wprojb, 262144);
  // 2) qkv GEMM (256^2 8-phase) -> q [B,H,N,D], kT/vT [B,H,D,N]
  gemm256<0><<<64 * 12, 512, 0, stream>>>(xb, wqkvb, 3072, q, kT, vT, nullptr, nullptr);
  // 3) kv = k^T v (split-K MFMA) + ksum partials (kv_part aliases dead xb)
  kv_mfma<<<1024, 256, 0, stream>>>(kT, vT, kv_part, ksum_p);
  // 4) reduce partials -> kvT bf16 [bh][80][64]
  cvt_kv<<<64, 256, 0, stream>>>(kv_part, ksum_p, kvTb);
  // 5) num/z MFMA -> attn bf16 [B,N,C]
  numz_mfma<<<2048, 256, 0, stream>>>(q, kvTb, attn);
  // 6) output projection (256^2 8-phase) + bias -> fp32 out
  gemm256<1><<<64 * 4, 512, 0, stream>>>(attn, wprojb, 1024, nullptr, nullptr, nullptr,
                                         b_proj, out);
}

// Round 4
// 309.465 us; speedup vs baseline: 1.4976x; 1.0251x over previous
//
#include <hip/hip_runtime.h>
#include <hip/hip_bf16.h>
#include <stdint.h>

// LinearAttention on MI355X (gfx950)
// x:[4,4096,1024]f32  w_qkv:[3072,1024]f32  w_proj:[1024,1024]f32  b_proj:[1024]f32
// out:[4,4096,1024]f32

typedef unsigned short u16;
typedef __attribute__((ext_vector_type(4))) float f32x4;
typedef __attribute__((ext_vector_type(8))) __bf16 bf16x8;
typedef __attribute__((ext_vector_type(4))) unsigned short us4;
typedef __attribute__((ext_vector_type(8))) unsigned short us8;

typedef __attribute__((address_space(3))) unsigned as3u;
typedef const __attribute__((address_space(1))) unsigned as1u;

__device__ __forceinline__ float bf2f(u16 u) {
  union { unsigned i; float f; } x; x.i = ((unsigned)u) << 16; return x.f;
}
__device__ __forceinline__ u16 f2bf(float f) {
  union { float f; unsigned i; } x; x.f = f;
  return (u16)((x.i + 0x7FFFu + ((x.i >> 16) & 1u)) >> 16);
}
__device__ __forceinline__ void gload16(const u16* g, u16* l) {
  __builtin_amdgcn_global_load_lds((as1u*)g, (as3u*)l, 16, 0, 0);
}
__device__ __forceinline__ bf16x8 ld8(const u16* p) { return *(const bf16x8*)p; }

#define BAR asm volatile("s_barrier" ::: "memory")
#define VMC4 asm volatile("s_waitcnt vmcnt(4)" ::: "memory")
#define VMC0 asm volatile("s_waitcnt vmcnt(0)" ::: "memory")

// ---------------- fp32 -> bf16 convert (vector x4) ----------------
__global__ __launch_bounds__(256) void cvt_kernel(const float* __restrict__ src,
                                                  u16* __restrict__ dst, int n4) {
  int i = blockIdx.x * 256 + threadIdx.x;
  if (i < n4) {
    f32x4 v = ((const f32x4*)src)[i];
    us4 o;
    o[0] = f2bf(v[0]); o[1] = f2bf(v[1]); o[2] = f2bf(v[2]); o[3] = f2bf(v[3]);
    ((us4*)dst)[i] = o;
  }
}

// ======== 256x256-tile bf16 MFMA GEMM, 8-phase schedule (m201 template) ========
// C[m,c] = sum_k A[m,k]*B[c,k], K=1024. 512 thr = 8 waves (2M x 4N).
// LDS: 2 dbuf x (A[256][64] + B[256][64]) = 128 KiB, XOR chunk-swizzle.
// XCD supertile: tm-fastest within each XCD chunk -> 8 A-panels (4MB) L2-resident.
// EPI==0: qkv epilogue (elu+1 on q,k; q [B,H,N,D] via LDS-bounce; kT/vT [B,H,D,N])
// EPI==1: proj epilogue (+bias, fp32 out)
template <int EPI>
__global__ __launch_bounds__(512) void gemm256(
    const u16* __restrict__ A, const u16* __restrict__ B, int Ncols,
    u16* __restrict__ oQ, u16* __restrict__ oKT, u16* __restrict__ oVT,
    const float* __restrict__ bias, float* __restrict__ oF) {
  constexpr int K = 1024;
  constexpr int NITER = 8;  // 16 K-tiles, 2 per iteration
  __shared__ u16 lds[2][2][256 * 64];  // [buf][0=A,1=B]

  // XCD supertile decode: nTm must be 64 (=8 XCD x 8 panels); tn = bid>>6
  const int bid = blockIdx.x;
  const int tm = (bid & 7) * 8 + ((bid >> 3) & 7);
  const int tn = bid >> 6;
  const int m0 = tm << 8, n0 = tn << 8;
  const int t = threadIdx.x;
  const int w = t >> 6, lane = t & 63;
  const int wm = w >> 2, wn = w & 3;
  const int l15 = lane & 15, l4 = lane >> 4;

  const u16* Ab = A + (size_t)m0 * K;
  const u16* Bb = B + (size_t)n0 * K;

  // staging source offsets: load l covers chunk c = l*512+t; row=c>>3, ch=c&7
  // physical LDS is linear; source chunk pre-swizzled: sch = ch ^ (row&7)
  int srcoff[2][2];
  #pragma unroll
  for (int l = 0; l < 2; ++l) {
    int c = l * 512 + t;
    int row = c >> 3, ch = c & 7;
    #pragma unroll
    for (int h = 0; h < 2; ++h) {
      int r = row + h * 128;
      srcoff[l][h] = r * K + (ch ^ (r & 7)) * 8;
    }
  }

#define STAGE(mat, buf, h, kt)                                                \
  {                                                                           \
    const u16* gsrc = ((mat) ? Bb : Ab) + (kt) * 64;                          \
    _Pragma("unroll") for (int l = 0; l < 2; ++l)                             \
        gload16(gsrc + srcoff[l][h],                                          \
                &lds[buf][mat][(l * 512 + w * 64) * 8 + (h) * 128 * 64]);     \
  }

#define LDA(buf, q)                                                           \
  _Pragma("unroll") for (int i = 0; i < 2; ++i)                               \
  _Pragma("unroll") for (int kk = 0; kk < 2; ++kk) {                          \
    int row = wm * 128 + (q) * 32 + i * 16 + l15;                             \
    int ch = (kk * 4 + l4) ^ (row & 7);                                       \
    a[i][kk] = ld8(&lds[buf][0][row * 64 + ch * 8]);                          \
  }

#define LDB(buf)                                                              \
  _Pragma("unroll") for (int j = 0; j < 4; ++j)                               \
  _Pragma("unroll") for (int kk = 0; kk < 2; ++kk) {                          \
    int row = wn * 64 + j * 16 + l15;                                         \
    int ch = (kk * 4 + l4) ^ (row & 7);                                       \
    b[j][kk] = ld8(&lds[buf][1][row * 64 + ch * 8]);                          \
  }

#define MFMA16(q)                                                             \
  __builtin_amdgcn_s_setprio(1);                                              \
  _Pragma("unroll") for (int i = 0; i < 2; ++i)                               \
  _Pragma("unroll") for (int kk = 0; kk < 2; ++kk)                            \
  _Pragma("unroll") for (int j = 0; j < 4; ++j)                               \
    acc[(q) * 2 + i][j] = __builtin_amdgcn_mfma_f32_16x16x32_bf16(            \
        a[i][kk], b[j][kk], acc[(q) * 2 + i][j], 0, 0, 0);                    \
  __builtin_amdgcn_s_setprio(0);

  f32x4 acc[8][4] = {};
  bf16x8 a[2][2], b[4][2];

  // prologue: tile0 (B then A) -> buf0, tile1 B -> buf1.  12 loads out.
  STAGE(1, 0, 0, 0); STAGE(1, 0, 1, 0);
  STAGE(0, 0, 0, 0); STAGE(0, 0, 1, 0);
  STAGE(1, 1, 0, 1); STAGE(1, 1, 1, 1);
  VMC4;  // drain B(0),A(0); leave B(1) in flight
  BAR;

  for (int J = 0; J < NITER; ++J) {
    const int t2 = 2 * J + 2, t3 = 2 * J + 3;
    const bool more = (J < NITER - 1);
    // ---- tile 2J from buf0 ----
    LDB(0); LDA(0, 0);
    STAGE(0, 1, 0, 2 * J + 1);
    BAR; MFMA16(0); BAR;
    LDA(0, 1);
    STAGE(0, 1, 1, 2 * J + 1);
    BAR; MFMA16(1); BAR;
    LDA(0, 2);
    if (more) STAGE(1, 0, 0, t2);
    BAR; MFMA16(2); BAR;
    LDA(0, 3);
    if (more) STAGE(1, 0, 1, t2);
    BAR; MFMA16(3);
    if (more) { VMC4; } else { VMC0; }
    BAR;
    // ---- tile 2J+1 from buf1 ----
    LDB(1); LDA(1, 0);
    if (more) STAGE(0, 0, 0, t2);
    BAR; MFMA16(0); BAR;
    LDA(1, 1);
    if (more) STAGE(0, 0, 1, t2);
    BAR; MFMA16(1); BAR;
    LDA(1, 2);
    if (more) STAGE(1, 1, 0, t3);
    BAR; MFMA16(2); BAR;
    LDA(1, 3);
    if (more) STAGE(1, 1, 1, t3);
    BAR; MFMA16(3);
    if (more) { VMC4; } else { VMC0; }
    BAR;
  }

  // epilogue: D frag mapping col=lane&15, row=(lane>>4)*4+reg  [HW-verified]
  if constexpr (EPI == 0) {
    const int part = n0 >> 10;
    if (part == 0) {
      // q: LDS-bounce -> coalesced us8 stores to [B,H,N,D]
      u16* sb = (u16*)lds;  // 256x256 bf16 = 128 KiB
      __syncthreads();      // K-loop LDS fully consumed
      #pragma unroll
      for (int fi = 0; fi < 8; ++fi) {
        #pragma unroll
        for (int j = 0; j < 4; ++j) {
          #pragma unroll
          for (int r = 0; r < 4; ++r) {
            int m = wm * 128 + fi * 16 + l4 * 4 + r;
            int c = wn * 64 + j * 16 + l15;
            float val = acc[fi][j][r];
            val = val > 0.f ? val + 1.f : __expf(val);  // elu(x)+1
            sb[m * 256 + (c ^ (((m >> 2) & 3) << 4))] = f2bf(val);
          }
        }
      }
      __syncthreads();
      #pragma unroll
      for (int i = 0; i < 16; ++i) {
        int idx = i * 512 + t;
        int rr = idx >> 5, g = idx & 31;
        int gs = g ^ (((rr >> 2) & 3) << 1);
        us8 vv = *(const us8*)&sb[rr * 256 + gs * 8];
        int n = (m0 + rr) & 4095, bb = (m0 + rr) >> 12;
        int c = n0 + g * 8;  // < 1024
        int h = c >> 6, d = c & 63;
        *(us8*)&oQ[(((size_t)(bb * 16 + h)) * 4096 + n) * 64 + d] = vv;
      }
    } else {
      // kT / vT: us4 stores along n into [B,H,D,N]
      #pragma unroll
      for (int j = 0; j < 4; ++j) {
        const int col = n0 + wn * 64 + j * 16 + l15;
        const int cc = col & 1023;
        const int h = cc >> 6, d = cc & 63;
        #pragma unroll
        for (int fi = 0; fi < 8; ++fi) {
          const int mbase = m0 + wm * 128 + fi * 16 + l4 * 4;
          const int bb = mbase >> 12, n = mbase & 4095;
          const int bh = bb * 16 + h;
          us4 o;
          #pragma unroll
          for (int r = 0; r < 4; ++r) {
            float val = acc[fi][j][r];
            if (part == 1) val = val > 0.f ? val + 1.f : __expf(val);
            o[r] = f2bf(val);
          }
          u16* dst = (part == 1) ? oKT : oVT;
          *(us4*)&dst[(((size_t)bh) * 64 + d) * 4096 + n] = o;
        }
      }
    }
  } else {
    #pragma unroll
    for (int fi = 0; fi < 8; ++fi) {
      const int mbase = m0 + wm * 128 + fi * 16 + l4 * 4;
      #pragma unroll
      for (int j = 0; j < 4; ++j) {
        const int col = n0 + wn * 64 + j * 16 + l15;
        #pragma unroll
        for (int r = 0; r < 4; ++r)
          oF[(size_t)(mbase + r) * 1024 + col] = acc[fi][j][r] + bias[col];
      }
    }
  }
#undef STAGE
#undef LDA
#undef LDB
#undef MFMA16
}

// ---------------- kv = kT @ vT^T per (b,h), split-K MFMA + ksum ----------------
__global__ __launch_bounds__(256) void kv_mfma(const u16* __restrict__ kTg,
                                               const u16* __restrict__ vTg,
                                               float* __restrict__ kv_part,
                                               float* __restrict__ ksum_part) {
  __shared__ u16 kTl[64 * 256];
  __shared__ u16 vTl[64 * 256];
  const int blk = blockIdx.x;
  const int bh = blk >> 4, s = blk & 15;
  const int n0 = s * 256;
  const int t = threadIdx.x;
  const int w = t >> 6, lane = t & 63;
  const int wr = w >> 1, wc = w & 1;
  const int l15 = lane & 15, l4 = lane >> 4;

  const u16* kg = kTg + ((size_t)bh * 64) * 4096 + n0;
  const u16* vg = vTg + ((size_t)bh * 64) * 4096 + n0;
  #pragma unroll
  for (int i = 0; i < 8; ++i) {
    int c = i * 256 + t;
    int row = c >> 5, ch = c & 31;
    int sch = (ch & ~7) | ((ch ^ row) & 7);
    gload16(kg + (size_t)row * 4096 + sch * 8, &kTl[(i * 256 + w * 64) * 8]);
    gload16(vg + (size_t)row * 4096 + sch * 8, &vTl[(i * 256 + w * 64) * 8]);
  }
  __syncthreads();

  {
    const int row = t >> 2, q4 = t & 3;
    float sum = 0.f;
    #pragma unroll
    for (int j = 0; j < 8; ++j) {
      int p = q4 * 8 + ((j + row) & 7);
      us8 u = *(const us8*)&kTl[row * 256 + p * 8];
      #pragma unroll
      for (int x = 0; x < 8; ++x) sum += bf2f(u[x]);
    }
    sum += __shfl_xor(sum, 1);
    sum += __shfl_xor(sum, 2);
    if ((t & 3) == 0) ksum_part[((size_t)s * 64 + bh) * 64 + row] = sum;
  }

  f32x4 acc[2][2] = {};
  #pragma unroll
  for (int kk = 0; kk < 8; ++kk) {
    bf16x8 a[2], b[2];
    #pragma unroll
    for (int i = 0; i < 2; ++i) {
      int row = wr * 32 + i * 16 + l15;
      int p = (kk * 4 + l4) ^ (row & 7);
      a[i] = ld8(&kTl[row * 256 + p * 8]);
    }
    #pragma unroll
    for (int j = 0; j < 2; ++j) {
      int row = wc * 32 + j * 16 + l15;
      int p = (kk * 4 + l4) ^ (row & 7);
      b[j] = ld8(&vTl[row * 256 + p * 8]);
    }
    #pragma unroll
    for (int i = 0; i < 2; ++i)
      #pragma unroll
      for (int j = 0; j < 2; ++j)
        acc[i][j] = __builtin_amdgcn_mfma_f32_16x16x32_bf16(a[i], b[j], acc[i][j], 0, 0, 0);
  }
  float* dst = kv_part + ((size_t)s * 64 + bh) * 4096;
  #pragma unroll
  for (int i = 0; i < 2; ++i)
    #pragma unroll
    for (int j = 0; j < 2; ++j)
      #pragma unroll
      for (int r = 0; r < 4; ++r) {
        int d = wr * 32 + i * 16 + l4 * 4 + r;
        int e = wc * 32 + j * 16 + l15;
        dst[e * 64 + d] = acc[i][j][r];
      }
}

// ---------------- reduce split-K partials -> kvT bf16 [bh][80][64] ----------------
__global__ __launch_bounds__(256) void cvt_kv(const float* __restrict__ kv_part,
                                              const float* __restrict__ ksum_part,
                                              u16* __restrict__ kvTb) {
  const int bh = blockIdx.x;
  const int t = threadIdx.x;
  #pragma unroll
  for (int i = 0; i < 20; ++i) {
    int idx = i * 256 + t;
    int row = idx >> 6, d = idx & 63;
    float s = 0.f;
    if (row < 64) {
      #pragma unroll
      for (int p = 0; p < 16; ++p)
        s += kv_part[((size_t)p * 64 + bh) * 4096 + idx];
    } else if (row == 64) {
      #pragma unroll
      for (int p = 0; p < 16; ++p)
        s += ksum_part[((size_t)p * 64 + bh) * 64 + d];
    }
    kvTb[(size_t)bh * 5120 + idx] = f2bf(s);
  }
}

// ---------------- num = q @ kvT, z via ksum-column, attn = num*z ----------------
__global__ __launch_bounds__(256) void numz_mfma(const u16* __restrict__ qg,
                                                 const u16* __restrict__ kvTb,
                                                 u16* __restrict__ attn) {
  __shared__ u16 ql[128 * 64];
  __shared__ u16 bl[80 * 64];
  const int blk = blockIdx.x;
  const int bh = blk >> 5, c5 = blk & 31;
  const int t = threadIdx.x;
  const int w = t >> 6, lane = t & 63;
  const int l15 = lane & 15, l4 = lane >> 4;
  const int bb = bh >> 4, h = bh & 15;

  const u16* qp = qg + ((size_t)bh * 4096 + c5 * 128) * 64;
  #pragma unroll
  for (int i = 0; i < 4; ++i) {
    int c = i * 256 + t;
    int row = c >> 3, ch = c & 7;
    gload16(qp + (size_t)row * 64 + ((ch ^ row) & 7) * 8, &ql[(i * 256 + w * 64) * 8]);
  }
  {
    const us4* bsrc = (const us4*)(kvTb + (size_t)bh * 5120);
    #pragma unroll
    for (int i = 0; i < 5; ++i) {
      int idx = i * 256 + t;
      int row = idx >> 4;
      ((us4*)bl)[idx ^ ((row & 7) << 1)] = bsrc[idx];
    }
  }
  __syncthreads();

  f32x4 acc[2][5] = {};
  #pragma unroll
  for (int kk = 0; kk < 2; ++kk) {
    bf16x8 a[2], b[5];
    #pragma unroll
    for (int i = 0; i < 2; ++i) {
      int row = w * 32 + i * 16 + l15;
      int p = (kk * 4 + l4) ^ (row & 7);
      a[i] = ld8(&ql[row * 64 + p * 8]);
    }
    #pragma unroll
    for (int j = 0; j < 5; ++j) {
      int row = j * 16 + l15;
      int p = (kk * 4 + l4) ^ (row & 7);
      b[j] = ld8(&bl[row * 64 + p * 8]);
    }
    #pragma unroll
    for (int i = 0; i < 2; ++i)
      #pragma unroll
      for (int j = 0; j < 5; ++j)
        acc[i][j] = __builtin_amdgcn_mfma_f32_16x16x32_bf16(a[i], b[j], acc[i][j], 0, 0, 0);
  }

  #pragma unroll
  for (int i = 0; i < 2; ++i)
    #pragma unroll
    for (int r = 0; r < 4; ++r) {
      int m = w * 32 + i * 16 + l4 * 4 + r;
      int n = c5 * 128 + m;
      float zv = __shfl(acc[i][4][r], lane & 48);
      float zz = 1.f / (zv + 1e-6f);
      u16* op = attn + ((size_t)bb * 4096 + n) * 1024 + h * 64;
      #pragma unroll
      for (int j = 0; j < 4; ++j)
        op[j * 16 + l15] = f2bf(acc[i][j][r] * zz);
    }
}

extern "C" void kernel_launch(void* const* d_in, const int* in_sizes, int n_in,
                              void* d_out, int out_size, void* d_ws, size_t ws_size,
                              hipStream_t stream) {
  const float* x = (const float*)d_in[0];
  const float* w_qkv = (const float*)d_in[1];
  const float* w_proj = (const float*)d_in[2];
  const float* b_proj = (const float*)d_in[3];
  float* out = (float*)d_out;
  char* ws = (char*)d_ws;

  // workspace layout (bytes)
  u16* xb        = (u16*)(ws);                 // 32MB  x bf16
  float* kv_part = (float*)(ws);               // alias: 16.8MB, live kv_mfma->cvt_kv
  u16* attn      = (u16*)(ws);                 // alias: 32MB, live numz->proj gemm
  u16* wqkvb     = (u16*)(ws + 33554432);      // 6MB
  u16* wprojb    = (u16*)(ws + 39845888);      // 2MB
  u16* q         = (u16*)(ws + 41943040);      // 32MB [B,H,N,D]
  u16* kT        = (u16*)(ws + 75497472);      // 32MB [B,H,D,N]
  u16* vT        = (u16*)(ws + 109051904);     // 32MB [B,H,D,N]
  float* ksum_p  = (float*)(ws + 142606336);   // 256KB [16][64][64]
  u16* kvTb      = (u16*)(ws + 142868480);     // 640KB [64][80][64]

  // 1) convert inputs to bf16
  cvt_kernel<<<16384, 256, 0, stream>>>(x, xb, 4194304);
  cvt_kernel<<<3072, 256, 0, stream>>>(w_qkv, wqkvb, 786432);
  cvt_kernel<<<1024, 256, 0, stream>>>(w_proj, wprojb, 262144);
  // 2) qkv GEMM (256^2 8-phase) -> q [B,H,N,D], kT/vT [B,H,D,N]
  gemm256<0><<<64 * 12, 512, 0, stream>>>(xb, wqkvb, 3072, q, kT, vT, nullptr, nullptr);
  // 3) kv = k^T v (split-K MFMA) + ksum partials (kv_part aliases dead xb)
  kv_mfma<<<1024, 256, 0, stream>>>(kT, vT, kv_part, ksum_p);
  // 4) reduce partials -> kvT bf16 [bh][80][64]
  cvt_kv<<<64, 256, 0, stream>>>(kv_part, ksum_p, kvTb);
  // 5) num/z MFMA -> attn bf16 [B,N,C]
  numz_mfma<<<2048, 256, 0, stream>>>(q, kvTb, attn);
  // 6) output projection (256^2 8-phase) + bias -> fp32 out
  gemm256<1><<<64 * 4, 512, 0, stream>>>(attn, wprojb, 1024, nullptr, nullptr, nullptr,
                                         b_proj, out);
}